// Round 3
// baseline (959.440 us; speedup 1.0000x reference)
//
#include <hip/hip_runtime.h>

typedef _Float16 f16_t;
typedef f16_t f16x4 __attribute__((ext_vector_type(4)));
typedef f16_t f16x8 __attribute__((ext_vector_type(8)));
typedef float f32x4 __attribute__((ext_vector_type(4)));

#define MFMA16(a, b, c) __builtin_amdgcn_mfma_f32_16x16x32_f16((a), (b), (c), 0, 0, 0)

// bf16 round (RNE) of an f32, result returned as f32 on the bf16 grid.
__device__ __forceinline__ float bfr(float x) { return (float)(__bf16)x; }

// ---------------------------------------------------------------------------
// Pack fp32 weight matrices into f16 MFMA B-fragment order, bf16-rounded first
// (bf16 values are exactly representable in f16 at these magnitudes).
// B-frag (kstep, ntile): lane l, elem j -> W[kstep*32 + (l>>4)*8 + j][ntile*16 + (l&15)]
// stored at dst[doff + ((kstep*NT + ntile)*64 + l)*8 + j]
// ---------------------------------------------------------------------------
__global__ void pack_weights_kernel(
    const float* __restrict__ ew0, const float* __restrict__ ew1,
    const float* __restrict__ ew2, const float* __restrict__ eL,
    const float* __restrict__ nw0, const float* __restrict__ nw1,
    const float* __restrict__ nw2, const float* __restrict__ nL,
    f16_t* __restrict__ dst)
{
    int tid = blockIdx.x * 256 + threadIdx.x;
    int fid = tid >> 6, lane = tid & 63;
    const float* src; int Ncols, foff, doff;
    if (fid < 192)      { src = ew0; Ncols = 256; foff = 0;   doff = 0;      }
    else if (fid < 320) { src = ew1; Ncols = 256; foff = 192; doff = 98304;  }
    else if (fid < 384) { src = ew2; Ncols = 128; foff = 320; doff = 163840; }
    else if (fid < 416) { src = eL;  Ncols = 128; foff = 384; doff = 196608; }
    else if (fid < 544) { src = nw0; Ncols = 256; foff = 416; doff = 212992; }
    else if (fid < 672) { src = nw1; Ncols = 256; foff = 544; doff = 278528; }
    else if (fid < 736) { src = nw2; Ncols = 128; foff = 672; doff = 344064; }
    else                { src = nL;  Ncols = 128; foff = 736; doff = 376832; }
    int f = fid - foff;
    int NT = Ncols >> 4;
    int kstep = f / NT, ntile = f - kstep * NT;
    int col = ntile * 16 + (lane & 15);
    int kbase = kstep * 32 + ((lane >> 4) << 3);
    f16x8 out;
    #pragma unroll
    for (int j = 0; j < 8; ++j)
        out[j] = (f16_t)bfr(src[(size_t)(kbase + j) * Ncols + col]);
    *reinterpret_cast<f16x8*>(dst + (size_t)doff + ((size_t)f * 64 + lane) * 8) = out;
}

// ---------------------------------------------------------------------------
// Edge kernel: 32 edges/block, 256 threads. Inputs bf16-rounded; intermediates
// kept at ~f32 precision via hi/lo f16 pairs (two MFMA passes).
// ---------------------------------------------------------------------------
__launch_bounds__(256, 1)
__global__ void edge_kernel(
    const float* __restrict__ vfeat, const float* __restrict__ efeat,
    const int* __restrict__ eidx,
    const float* __restrict__ lng, const float* __restrict__ lnb,
    const f16_t* __restrict__ pw,
    const float* __restrict__ b0, const float* __restrict__ b1,
    const float* __restrict__ b2,
    float* __restrict__ out_e, float* __restrict__ aggr, float* __restrict__ cnts,
    int Ee)
{
    __shared__ f16_t XHI[32 * 392];
    __shared__ f16_t XLO[32 * 392];
    __shared__ f16_t H1HI[32 * 264];
    __shared__ f16_t H1LO[32 * 264];
    __shared__ int cidx[32];

    const int t    = threadIdx.x;
    const int lane = t & 63;
    const int wv   = t >> 6;
    const size_t ebase = (size_t)blockIdx.x * 32;

    // ---- phase 0: gather + bf16-round (keep in regs) + LN stats
    const int el = t >> 3;
    const int pp = t & 7;
    const size_t eg = ebase + el;
    const int c0 = eidx[(size_t)Ee + eg];

    float4 d[12];
    float s = 0.f, sq = 0.f;
    {
        const int r0 = eidx[eg];
        const float4* e4 = (const float4*)efeat;
        const float4* v4 = (const float4*)vfeat;
        #pragma unroll
        for (int i = 0; i < 12; ++i) {
            int q = i * 8 + pp;                 // f4 index within 96 (=384 floats)
            float4 r;
            if (q < 32)      r = e4[eg * 32 + q];
            else if (q < 64) r = v4[(size_t)r0 * 32 + (q - 32)];
            else             r = v4[(size_t)c0 * 32 + (q - 64)];
            d[i].x = bfr(r.x); d[i].y = bfr(r.y); d[i].z = bfr(r.z); d[i].w = bfr(r.w);
            s  += d[i].x + d[i].y + d[i].z + d[i].w;
            sq += d[i].x*d[i].x + d[i].y*d[i].y + d[i].z*d[i].z + d[i].w*d[i].w;
        }
        if (pp == 0) {
            cidx[el] = c0;
            unsafeAtomicAdd(&cnts[c0], 1.0f);
        }
    }
    #pragma unroll
    for (int off = 1; off < 8; off <<= 1) {
        s  += __shfl_xor(s, off);
        sq += __shfl_xor(sq, off);
    }
    const float mean = s * (1.f / 384.f);
    const float rstd = rsqrtf(sq * (1.f / 384.f) - mean * mean + 1e-5f);

    // ---- phase 1: normalize in f32, split hi/lo, store to LDS
    {
        const float4* g4p = (const float4*)lng;
        const float4* bpp = (const float4*)lnb;
        #pragma unroll
        for (int i = 0; i < 12; ++i) {
            int q = i * 8 + pp;
            float4 g = g4p[q]; float4 bb = bpp[q];
            float y0 = (d[i].x - mean) * rstd * bfr(g.x) + bfr(bb.x);
            float y1 = (d[i].y - mean) * rstd * bfr(g.y) + bfr(bb.y);
            float y2 = (d[i].z - mean) * rstd * bfr(g.z) + bfr(bb.z);
            float y3 = (d[i].w - mean) * rstd * bfr(g.w) + bfr(bb.w);
            f16x4 hi, lo;
            hi[0] = (f16_t)y0; lo[0] = (f16_t)(y0 - (float)hi[0]);
            hi[1] = (f16_t)y1; lo[1] = (f16_t)(y1 - (float)hi[1]);
            hi[2] = (f16_t)y2; lo[2] = (f16_t)(y2 - (float)hi[2]);
            hi[3] = (f16_t)y3; lo[3] = (f16_t)(y3 - (float)hi[3]);
            *reinterpret_cast<f16x4*>(&XHI[el * 392 + q * 4]) = hi;
            *reinterpret_cast<f16x4*>(&XLO[el * 392 + q * 4]) = lo;
        }
    }
    __syncthreads();

    const int r16 = lane & 15;
    const int g4i = lane >> 4;

    // ---- layer 1: x[32,384] @ ew0 -> h1[32,256]; wave wv covers cols [wv*64,+64)
    {
        f32x4 aH[2][4] = {}, aL[2][4] = {};
        const f16_t* bw = pw;                       // ew0
        for (int ks = 0; ks < 12; ++ks) {
            f16x8 a0h = *reinterpret_cast<const f16x8*>(&XHI[r16 * 392 + ks * 32 + g4i * 8]);
            f16x8 a0l = *reinterpret_cast<const f16x8*>(&XLO[r16 * 392 + ks * 32 + g4i * 8]);
            f16x8 a1h = *reinterpret_cast<const f16x8*>(&XHI[(16 + r16) * 392 + ks * 32 + g4i * 8]);
            f16x8 a1l = *reinterpret_cast<const f16x8*>(&XLO[(16 + r16) * 392 + ks * 32 + g4i * 8]);
            #pragma unroll
            for (int n = 0; n < 4; ++n) {
                f16x8 b = *reinterpret_cast<const f16x8*>(
                    &bw[((size_t)(ks * 16 + wv * 4 + n) * 64 + lane) * 8]);
                aH[0][n] = MFMA16(a0h, b, aH[0][n]);
                aL[0][n] = MFMA16(a0l, b, aL[0][n]);
                aH[1][n] = MFMA16(a1h, b, aH[1][n]);
                aL[1][n] = MFMA16(a1l, b, aL[1][n]);
            }
        }
        #pragma unroll
        for (int n = 0; n < 4; ++n) {
            int c = wv * 64 + n * 16 + r16;
            float bias = bfr(b0[c]);
            #pragma unroll
            for (int m = 0; m < 2; ++m)
                #pragma unroll
                for (int qi = 0; qi < 4; ++qi) {
                    int rr = m * 16 + g4i * 4 + qi;
                    float h = fmaxf(aH[m][n][qi] + aL[m][n][qi] + bias, 0.f);
                    f16_t hi = (f16_t)h;
                    H1HI[rr * 264 + c] = hi;
                    H1LO[rr * 264 + c] = (f16_t)(h - (float)hi);
                }
        }
    }
    __syncthreads();

    // ---- layer 2: h1 @ ew1 -> h2 (into XHI/XLO, stride 264)
    {
        f32x4 aH[2][4] = {}, aL[2][4] = {};
        const f16_t* bw = pw + 98304;               // ew1
        for (int ks = 0; ks < 8; ++ks) {
            f16x8 a0h = *reinterpret_cast<const f16x8*>(&H1HI[r16 * 264 + ks * 32 + g4i * 8]);
            f16x8 a0l = *reinterpret_cast<const f16x8*>(&H1LO[r16 * 264 + ks * 32 + g4i * 8]);
            f16x8 a1h = *reinterpret_cast<const f16x8*>(&H1HI[(16 + r16) * 264 + ks * 32 + g4i * 8]);
            f16x8 a1l = *reinterpret_cast<const f16x8*>(&H1LO[(16 + r16) * 264 + ks * 32 + g4i * 8]);
            #pragma unroll
            for (int n = 0; n < 4; ++n) {
                f16x8 b = *reinterpret_cast<const f16x8*>(
                    &bw[((size_t)(ks * 16 + wv * 4 + n) * 64 + lane) * 8]);
                aH[0][n] = MFMA16(a0h, b, aH[0][n]);
                aL[0][n] = MFMA16(a0l, b, aL[0][n]);
                aH[1][n] = MFMA16(a1h, b, aH[1][n]);
                aL[1][n] = MFMA16(a1l, b, aL[1][n]);
            }
        }
        __syncthreads();   // all layer-2 reads done before overwriting XHI/XLO
        #pragma unroll
        for (int n = 0; n < 4; ++n) {
            int c = wv * 64 + n * 16 + r16;
            float bias = bfr(b1[c]);
            #pragma unroll
            for (int m = 0; m < 2; ++m)
                #pragma unroll
                for (int qi = 0; qi < 4; ++qi) {
                    int rr = m * 16 + g4i * 4 + qi;
                    float h = fmaxf(aH[m][n][qi] + aL[m][n][qi] + bias, 0.f);
                    f16_t hi = (f16_t)h;
                    XHI[rr * 264 + c] = hi;
                    XLO[rr * 264 + c] = (f16_t)(h - (float)hi);
                }
        }
    }
    __syncthreads();

    // ---- layer 3 + residual: relu(h2 @ ew2 + b2) + e @ eLin ; cols [wv*32,+32)
    {
        f32x4 fH[2][2] = {}, fL[2][2] = {}, accR[2][2] = {};
        const f16_t* bw = pw + 163840;              // ew2 (NT=8)
        for (int ks = 0; ks < 8; ++ks) {
            f16x8 a0h = *reinterpret_cast<const f16x8*>(&XHI[r16 * 264 + ks * 32 + g4i * 8]);
            f16x8 a0l = *reinterpret_cast<const f16x8*>(&XLO[r16 * 264 + ks * 32 + g4i * 8]);
            f16x8 a1h = *reinterpret_cast<const f16x8*>(&XHI[(16 + r16) * 264 + ks * 32 + g4i * 8]);
            f16x8 a1l = *reinterpret_cast<const f16x8*>(&XLO[(16 + r16) * 264 + ks * 32 + g4i * 8]);
            #pragma unroll
            for (int n = 0; n < 2; ++n) {
                f16x8 b = *reinterpret_cast<const f16x8*>(
                    &bw[((size_t)(ks * 8 + wv * 2 + n) * 64 + lane) * 8]);
                fH[0][n] = MFMA16(a0h, b, fH[0][n]);
                fL[0][n] = MFMA16(a0l, b, fL[0][n]);
                fH[1][n] = MFMA16(a1h, b, fH[1][n]);
                fL[1][n] = MFMA16(a1l, b, fL[1][n]);
            }
        }
        const f16_t* bwL = pw + 196608;             // eLin (NT=8)
        for (int ks = 0; ks < 4; ++ks) {
            f16x8 a[2];
            #pragma unroll
            for (int m = 0; m < 2; ++m) {
                const float* src = &efeat[(ebase + (size_t)(m * 16 + r16)) * 128 + ks * 32 + g4i * 8];
                float4 f0 = *(const float4*)src;
                float4 f1 = *(const float4*)(src + 4);
                f16x8 av;
                av[0] = (f16_t)bfr(f0.x); av[1] = (f16_t)bfr(f0.y);
                av[2] = (f16_t)bfr(f0.z); av[3] = (f16_t)bfr(f0.w);
                av[4] = (f16_t)bfr(f1.x); av[5] = (f16_t)bfr(f1.y);
                av[6] = (f16_t)bfr(f1.z); av[7] = (f16_t)bfr(f1.w);
                a[m] = av;
            }
            #pragma unroll
            for (int n = 0; n < 2; ++n) {
                f16x8 b = *reinterpret_cast<const f16x8*>(
                    &bwL[((size_t)(ks * 8 + wv * 2 + n) * 64 + lane) * 8]);
                accR[0][n] = MFMA16(a[0], b, accR[0][n]);
                accR[1][n] = MFMA16(a[1], b, accR[1][n]);
            }
        }
        #pragma unroll
        for (int n = 0; n < 2; ++n) {
            int c = wv * 32 + n * 16 + r16;
            float bias = bfr(b2[c]);
            #pragma unroll
            for (int m = 0; m < 2; ++m)
                #pragma unroll
                for (int qi = 0; qi < 4; ++qi) {
                    int rr = m * 16 + g4i * 4 + qi;
                    float val = accR[m][n][qi] +
                                fmaxf(fH[m][n][qi] + fL[m][n][qi] + bias, 0.f);
                    size_t eg2 = ebase + rr;
                    out_e[eg2 * 128 + c] = val;
                    unsafeAtomicAdd(&aggr[(size_t)cidx[rr] * 128 + c], val);
                }
        }
    }
}

// ---------------------------------------------------------------------------
// Node kernel: 32 nodes/block. node_in = [aggr/clip(cnt) (f32) | bf16(v)].
// ---------------------------------------------------------------------------
__launch_bounds__(256, 1)
__global__ void node_kernel(
    const float* __restrict__ vfeat, const float* __restrict__ aggr,
    const float* __restrict__ cnts,
    const float* __restrict__ lng, const float* __restrict__ lnb,
    const f16_t* __restrict__ pw,                   // node weight base (nw0)
    const float* __restrict__ b0, const float* __restrict__ b1,
    const float* __restrict__ b2,
    float* __restrict__ out_v, int Nn)
{
    __shared__ f16_t XHI[32 * 264];
    __shared__ f16_t XLO[32 * 264];
    __shared__ f16_t H1HI[32 * 264];
    __shared__ f16_t H1LO[32 * 264];

    const int t    = threadIdx.x;
    const int lane = t & 63;
    const int wv   = t >> 6;
    const size_t nbase = (size_t)blockIdx.x * 32;

    const int nl = t >> 3;
    const int pp = t & 7;
    const size_t ng = nbase + nl;
    const bool valid = ng < (size_t)Nn;

    float4 d[8];
    float s = 0.f, sq = 0.f;
    {
        float cmax = 1.f;
        if (valid) cmax = fmaxf(cnts[ng], 1.f);
        const float4* a4 = (const float4*)aggr;
        const float4* v4 = (const float4*)vfeat;
        #pragma unroll
        for (int i = 0; i < 8; ++i) {
            int q = i * 8 + pp;                    // f4 index within 64 (=256 floats)
            float4 r = make_float4(0.f, 0.f, 0.f, 0.f);
            if (valid) {
                if (q < 32) {
                    r = a4[ng * 32 + q];
                    r.x = r.x / cmax; r.y = r.y / cmax;
                    r.z = r.z / cmax; r.w = r.w / cmax;   // f32, not rounded (derived)
                } else {
                    float4 rv = v4[ng * 32 + (q - 32)];
                    r.x = bfr(rv.x); r.y = bfr(rv.y); r.z = bfr(rv.z); r.w = bfr(rv.w);
                }
            }
            d[i] = r;
            s  += r.x + r.y + r.z + r.w;
            sq += r.x*r.x + r.y*r.y + r.z*r.z + r.w*r.w;
        }
    }
    #pragma unroll
    for (int off = 1; off < 8; off <<= 1) {
        s  += __shfl_xor(s, off);
        sq += __shfl_xor(sq, off);
    }
    const float mean = s * (1.f / 256.f);
    const float rstd = rsqrtf(sq * (1.f / 256.f) - mean * mean + 1e-5f);
    {
        const float4* g4p = (const float4*)lng;
        const float4* bpp = (const float4*)lnb;
        #pragma unroll
        for (int i = 0; i < 8; ++i) {
            int q = i * 8 + pp;
            float4 g = g4p[q]; float4 bb = bpp[q];
            float y0 = (d[i].x - mean) * rstd * bfr(g.x) + bfr(bb.x);
            float y1 = (d[i].y - mean) * rstd * bfr(g.y) + bfr(bb.y);
            float y2 = (d[i].z - mean) * rstd * bfr(g.z) + bfr(bb.z);
            float y3 = (d[i].w - mean) * rstd * bfr(g.w) + bfr(bb.w);
            f16x4 hi, lo;
            hi[0] = (f16_t)y0; lo[0] = (f16_t)(y0 - (float)hi[0]);
            hi[1] = (f16_t)y1; lo[1] = (f16_t)(y1 - (float)hi[1]);
            hi[2] = (f16_t)y2; lo[2] = (f16_t)(y2 - (float)hi[2]);
            hi[3] = (f16_t)y3; lo[3] = (f16_t)(y3 - (float)hi[3]);
            *reinterpret_cast<f16x4*>(&XHI[nl * 264 + q * 4]) = hi;
            *reinterpret_cast<f16x4*>(&XLO[nl * 264 + q * 4]) = lo;
        }
    }
    __syncthreads();

    const int r16 = lane & 15;
    const int g4i = lane >> 4;

    // ---- layer 1
    {
        f32x4 aH[2][4] = {}, aL[2][4] = {};
        const f16_t* bw = pw;                       // nw0
        for (int ks = 0; ks < 8; ++ks) {
            f16x8 a0h = *reinterpret_cast<const f16x8*>(&XHI[r16 * 264 + ks * 32 + g4i * 8]);
            f16x8 a0l = *reinterpret_cast<const f16x8*>(&XLO[r16 * 264 + ks * 32 + g4i * 8]);
            f16x8 a1h = *reinterpret_cast<const f16x8*>(&XHI[(16 + r16) * 264 + ks * 32 + g4i * 8]);
            f16x8 a1l = *reinterpret_cast<const f16x8*>(&XLO[(16 + r16) * 264 + ks * 32 + g4i * 8]);
            #pragma unroll
            for (int n = 0; n < 4; ++n) {
                f16x8 b = *reinterpret_cast<const f16x8*>(
                    &bw[((size_t)(ks * 16 + wv * 4 + n) * 64 + lane) * 8]);
                aH[0][n] = MFMA16(a0h, b, aH[0][n]);
                aL[0][n] = MFMA16(a0l, b, aL[0][n]);
                aH[1][n] = MFMA16(a1h, b, aH[1][n]);
                aL[1][n] = MFMA16(a1l, b, aL[1][n]);
            }
        }
        #pragma unroll
        for (int n = 0; n < 4; ++n) {
            int c = wv * 64 + n * 16 + r16;
            float bias = bfr(b0[c]);
            #pragma unroll
            for (int m = 0; m < 2; ++m)
                #pragma unroll
                for (int qi = 0; qi < 4; ++qi) {
                    int rr = m * 16 + g4i * 4 + qi;
                    float h = fmaxf(aH[m][n][qi] + aL[m][n][qi] + bias, 0.f);
                    f16_t hi = (f16_t)h;
                    H1HI[rr * 264 + c] = hi;
                    H1LO[rr * 264 + c] = (f16_t)(h - (float)hi);
                }
        }
    }
    __syncthreads();

    // ---- layer 2 (into XHI/XLO)
    {
        f32x4 aH[2][4] = {}, aL[2][4] = {};
        const f16_t* bw = pw + 65536;               // nw1
        for (int ks = 0; ks < 8; ++ks) {
            f16x8 a0h = *reinterpret_cast<const f16x8*>(&H1HI[r16 * 264 + ks * 32 + g4i * 8]);
            f16x8 a0l = *reinterpret_cast<const f16x8*>(&H1LO[r16 * 264 + ks * 32 + g4i * 8]);
            f16x8 a1h = *reinterpret_cast<const f16x8*>(&H1HI[(16 + r16) * 264 + ks * 32 + g4i * 8]);
            f16x8 a1l = *reinterpret_cast<const f16x8*>(&H1LO[(16 + r16) * 264 + ks * 32 + g4i * 8]);
            #pragma unroll
            for (int n = 0; n < 4; ++n) {
                f16x8 b = *reinterpret_cast<const f16x8*>(
                    &bw[((size_t)(ks * 16 + wv * 4 + n) * 64 + lane) * 8]);
                aH[0][n] = MFMA16(a0h, b, aH[0][n]);
                aL[0][n] = MFMA16(a0l, b, aL[0][n]);
                aH[1][n] = MFMA16(a1h, b, aH[1][n]);
                aL[1][n] = MFMA16(a1l, b, aL[1][n]);
            }
        }
        __syncthreads();
        #pragma unroll
        for (int n = 0; n < 4; ++n) {
            int c = wv * 64 + n * 16 + r16;
            float bias = bfr(b1[c]);
            #pragma unroll
            for (int m = 0; m < 2; ++m)
                #pragma unroll
                for (int qi = 0; qi < 4; ++qi) {
                    int rr = m * 16 + g4i * 4 + qi;
                    float h = fmaxf(aH[m][n][qi] + aL[m][n][qi] + bias, 0.f);
                    f16_t hi = (f16_t)h;
                    XHI[rr * 264 + c] = hi;
                    XLO[rr * 264 + c] = (f16_t)(h - (float)hi);
                }
        }
    }
    __syncthreads();

    // ---- layer 3 + residual
    {
        f32x4 fH[2][2] = {}, fL[2][2] = {}, accR[2][2] = {};
        const f16_t* bw = pw + 131072;              // nw2 (NT=8)
        for (int ks = 0; ks < 8; ++ks) {
            f16x8 a0h = *reinterpret_cast<const f16x8*>(&XHI[r16 * 264 + ks * 32 + g4i * 8]);
            f16x8 a0l = *reinterpret_cast<const f16x8*>(&XLO[r16 * 264 + ks * 32 + g4i * 8]);
            f16x8 a1h = *reinterpret_cast<const f16x8*>(&XHI[(16 + r16) * 264 + ks * 32 + g4i * 8]);
            f16x8 a1l = *reinterpret_cast<const f16x8*>(&XLO[(16 + r16) * 264 + ks * 32 + g4i * 8]);
            #pragma unroll
            for (int n = 0; n < 2; ++n) {
                f16x8 b = *reinterpret_cast<const f16x8*>(
                    &bw[((size_t)(ks * 8 + wv * 2 + n) * 64 + lane) * 8]);
                fH[0][n] = MFMA16(a0h, b, fH[0][n]);
                fL[0][n] = MFMA16(a0l, b, fL[0][n]);
                fH[1][n] = MFMA16(a1h, b, fH[1][n]);
                fL[1][n] = MFMA16(a1l, b, fL[1][n]);
            }
        }
        const f16_t* bwL = pw + 163840;             // nLin (NT=8)
        for (int ks = 0; ks < 4; ++ks) {
            f16x8 a[2];
            #pragma unroll
            for (int m = 0; m < 2; ++m) {
                size_t rv = nbase + (size_t)(m * 16 + r16);
                if (rv >= (size_t)Nn) rv = (size_t)Nn - 1;   // clamp (rows unused)
                const float* src = &vfeat[rv * 128 + ks * 32 + g4i * 8];
                float4 f0 = *(const float4*)src;
                float4 f1 = *(const float4*)(src + 4);
                f16x8 av;
                av[0] = (f16_t)bfr(f0.x); av[1] = (f16_t)bfr(f0.y);
                av[2] = (f16_t)bfr(f0.z); av[3] = (f16_t)bfr(f0.w);
                av[4] = (f16_t)bfr(f1.x); av[5] = (f16_t)bfr(f1.y);
                av[6] = (f16_t)bfr(f1.z); av[7] = (f16_t)bfr(f1.w);
                a[m] = av;
            }
            #pragma unroll
            for (int n = 0; n < 2; ++n) {
                f16x8 b = *reinterpret_cast<const f16x8*>(
                    &bwL[((size_t)(ks * 8 + wv * 2 + n) * 64 + lane) * 8]);
                accR[0][n] = MFMA16(a[0], b, accR[0][n]);
                accR[1][n] = MFMA16(a[1], b, accR[1][n]);
            }
        }
        #pragma unroll
        for (int n = 0; n < 2; ++n) {
            int c = wv * 32 + n * 16 + r16;
            float bias = bfr(b2[c]);
            #pragma unroll
            for (int m = 0; m < 2; ++m)
                #pragma unroll
                for (int qi = 0; qi < 4; ++qi) {
                    int rr = m * 16 + g4i * 4 + qi;
                    size_t ng2 = nbase + rr;
                    if (ng2 < (size_t)Nn) {
                        float val = accR[m][n][qi] +
                                    fmaxf(fH[m][n][qi] + fL[m][n][qi] + bias, 0.f);
                        out_v[ng2 * 128 + c] = val;
                    }
                }
        }
    }
}

// ---------------------------------------------------------------------------
extern "C" void kernel_launch(void* const* d_in, const int* in_sizes, int n_in,
                              void* d_out, int out_size, void* d_ws, size_t ws_size,
                              hipStream_t stream)
{
    const float* v    = (const float*)d_in[0];
    const float* e    = (const float*)d_in[1];
    const int*   eidx = (const int*)d_in[2];
    const float* elng = (const float*)d_in[3];
    const float* elnb = (const float*)d_in[4];
    const float* ew0  = (const float*)d_in[5];
    const float* eb0  = (const float*)d_in[6];
    const float* ew1  = (const float*)d_in[7];
    const float* eb1  = (const float*)d_in[8];
    const float* ew2  = (const float*)d_in[9];
    const float* eb2  = (const float*)d_in[10];
    const float* eLin = (const float*)d_in[11];
    const float* nlng = (const float*)d_in[12];
    const float* nlnb = (const float*)d_in[13];
    const float* nw0  = (const float*)d_in[14];
    const float* nb0  = (const float*)d_in[15];
    const float* nw1  = (const float*)d_in[16];
    const float* nb1  = (const float*)d_in[17];
    const float* nw2  = (const float*)d_in[18];
    const float* nb2  = (const float*)d_in[19];
    const float* nLin = (const float*)d_in[20];

    const int Nn = in_sizes[0] / 128;
    const int Ee = in_sizes[1] / 128;

    float* out_v = (float*)d_out;
    float* out_e = out_v + (size_t)Nn * 128;

    float* aggr = (float*)d_ws;                       // [Nn][128] f32
    float* cnts = aggr + (size_t)Nn * 128;            // [Nn] f32
    f16_t* packw = (f16_t*)((char*)d_ws + (size_t)Nn * 129 * 4);  // 393216 f16

    hipMemsetAsync(d_ws, 0, (size_t)Nn * 129 * 4, stream);

    pack_weights_kernel<<<192, 256, 0, stream>>>(ew0, ew1, ew2, eLin,
                                                 nw0, nw1, nw2, nLin, packw);

    edge_kernel<<<Ee / 32, 256, 0, stream>>>(v, e, eidx, elng, elnb, packw,
                                             eb0, eb1, eb2, out_e, aggr, cnts, Ee);

    node_kernel<<<(Nn + 31) / 32, 256, 0, stream>>>(v, aggr, cnts, nlng, nlnb,
                                                    packw + 212992, nb0, nb1, nb2,
                                                    out_v, Nn);
}

// Round 4
// 468.197 us; speedup vs baseline: 2.0492x; 2.0492x over previous
//
#include <hip/hip_runtime.h>

typedef _Float16 f16_t;
typedef f16_t f16x4 __attribute__((ext_vector_type(4)));
typedef f16_t f16x8 __attribute__((ext_vector_type(8)));
typedef float f32x4 __attribute__((ext_vector_type(4)));

#define MFMA16(a, b, c) __builtin_amdgcn_mfma_f32_16x16x32_f16((a), (b), (c), 0, 0, 0)

// bf16 round (RNE) of an f32 — matches the reference harness's input rounding.
// bf16 values at these magnitudes are exactly representable in f16.
__device__ __forceinline__ float bfr(float x) { return (float)(__bf16)x; }

// ---------------------------------------------------------------------------
// Pack fp32 weight matrices into f16 MFMA B-fragment order, bf16-rounded.
// B-frag (kstep, ntile): lane l, elem j -> W[kstep*32 + (l>>4)*8 + j][ntile*16 + (l&15)]
// stored at dst[doff + ((kstep*NT + ntile)*64 + l)*8 + j]
// ---------------------------------------------------------------------------
__global__ void pack_weights_kernel(
    const float* __restrict__ ew0, const float* __restrict__ ew1,
    const float* __restrict__ ew2, const float* __restrict__ eL,
    const float* __restrict__ nw0, const float* __restrict__ nw1,
    const float* __restrict__ nw2, const float* __restrict__ nL,
    f16_t* __restrict__ dst)
{
    int tid = blockIdx.x * 256 + threadIdx.x;
    int fid = tid >> 6, lane = tid & 63;
    const float* src; int Ncols, foff, doff;
    if (fid < 192)      { src = ew0; Ncols = 256; foff = 0;   doff = 0;      }
    else if (fid < 320) { src = ew1; Ncols = 256; foff = 192; doff = 98304;  }
    else if (fid < 384) { src = ew2; Ncols = 128; foff = 320; doff = 163840; }
    else if (fid < 416) { src = eL;  Ncols = 128; foff = 384; doff = 196608; }
    else if (fid < 544) { src = nw0; Ncols = 256; foff = 416; doff = 212992; }
    else if (fid < 672) { src = nw1; Ncols = 256; foff = 544; doff = 278528; }
    else if (fid < 736) { src = nw2; Ncols = 128; foff = 672; doff = 344064; }
    else                { src = nL;  Ncols = 128; foff = 736; doff = 376832; }
    int f = fid - foff;
    int NT = Ncols >> 4;
    int kstep = f / NT, ntile = f - kstep * NT;
    int col = ntile * 16 + (lane & 15);
    int kbase = kstep * 32 + ((lane >> 4) << 3);
    f16x8 out;
    #pragma unroll
    for (int j = 0; j < 8; ++j)
        out[j] = (f16_t)bfr(src[(size_t)(kbase + j) * Ncols + col]);
    *reinterpret_cast<f16x8*>(dst + (size_t)doff + ((size_t)f * 64 + lane) * 8) = out;
}

// ---------------------------------------------------------------------------
// Edge kernel: 32 edges/block, 256 threads (4 waves), 3 blocks/CU.
// Inputs bf16-rounded; intermediates single-pass f16; f32 accumulation.
// LDS: X [32][392] (LN'd concat; reused as h2 w/ stride 264), H1 [32][264],
//      ER [32][136] (raw bf16 e for the residual matmul).
// ---------------------------------------------------------------------------
__launch_bounds__(256, 3)
__global__ void edge_kernel(
    const float* __restrict__ vfeat, const float* __restrict__ efeat,
    const int* __restrict__ eidx,
    const float* __restrict__ lng, const float* __restrict__ lnb,
    const f16_t* __restrict__ pw,
    const float* __restrict__ b0, const float* __restrict__ b1,
    const float* __restrict__ b2,
    float* __restrict__ out_e, float* __restrict__ aggr, float* __restrict__ cnts,
    int Ee)
{
    __shared__ f16_t X[32 * 392];
    __shared__ f16_t H1[32 * 264];
    __shared__ f16_t ER[32 * 136];
    __shared__ int cidx[32];

    const int t    = threadIdx.x;
    const int lane = t & 63;
    const int wv   = t >> 6;
    const size_t ebase = (size_t)blockIdx.x * 32;

    // ---- phase 0: gather + bf16-round (keep in regs) + LN stats + stage raw e
    const int el = t >> 3;
    const int pp = t & 7;
    const size_t eg = ebase + el;
    const int r0 = eidx[eg];
    const int c0 = eidx[(size_t)Ee + eg];

    float4 d[12];
    float s = 0.f, sq = 0.f;
    {
        const float4* e4 = (const float4*)efeat;
        const float4* v4 = (const float4*)vfeat;
        #pragma unroll
        for (int i = 0; i < 12; ++i) {
            int q = i * 8 + pp;                 // f4 index within 96 (=384 floats)
            float4 r;
            if (q < 32)      r = e4[eg * 32 + q];
            else if (q < 64) r = v4[(size_t)r0 * 32 + (q - 32)];
            else             r = v4[(size_t)c0 * 32 + (q - 64)];
            d[i].x = bfr(r.x); d[i].y = bfr(r.y); d[i].z = bfr(r.z); d[i].w = bfr(r.w);
            if (q < 32) {
                f16x4 ev;
                ev[0] = (f16_t)d[i].x; ev[1] = (f16_t)d[i].y;
                ev[2] = (f16_t)d[i].z; ev[3] = (f16_t)d[i].w;
                *reinterpret_cast<f16x4*>(&ER[el * 136 + q * 4]) = ev;
            }
            s  += d[i].x + d[i].y + d[i].z + d[i].w;
            sq += d[i].x*d[i].x + d[i].y*d[i].y + d[i].z*d[i].z + d[i].w*d[i].w;
        }
        if (pp == 0) {
            cidx[el] = c0;
            unsafeAtomicAdd(&cnts[c0], 1.0f);
        }
    }
    #pragma unroll
    for (int off = 1; off < 8; off <<= 1) {
        s  += __shfl_xor(s, off);
        sq += __shfl_xor(sq, off);
    }
    const float mean = s * (1.f / 384.f);
    const float rstd = 1.f / sqrtf(sq * (1.f / 384.f) - mean * mean + 1e-5f);

    // ---- phase 1: normalize in f32, store f16 to LDS
    {
        const float4* g4p = (const float4*)lng;
        const float4* bpp = (const float4*)lnb;
        #pragma unroll
        for (int i = 0; i < 12; ++i) {
            int q = i * 8 + pp;
            float4 g = g4p[q]; float4 bb = bpp[q];
            f16x4 y;
            y[0] = (f16_t)((d[i].x - mean) * rstd * bfr(g.x) + bfr(bb.x));
            y[1] = (f16_t)((d[i].y - mean) * rstd * bfr(g.y) + bfr(bb.y));
            y[2] = (f16_t)((d[i].z - mean) * rstd * bfr(g.z) + bfr(bb.z));
            y[3] = (f16_t)((d[i].w - mean) * rstd * bfr(g.w) + bfr(bb.w));
            *reinterpret_cast<f16x4*>(&X[el * 392 + q * 4]) = y;
        }
    }
    __syncthreads();

    const int r16 = lane & 15;
    const int g4i = lane >> 4;

    // ---- layer 1: x[32,384] @ ew0 -> h1[32,256]; wave wv covers cols [wv*64,+64)
    {
        f32x4 acc[2][4] = {};
        const f16_t* bw = pw;                       // ew0
        for (int ks = 0; ks < 12; ++ks) {
            f16x8 a0 = *reinterpret_cast<const f16x8*>(&X[r16 * 392 + ks * 32 + g4i * 8]);
            f16x8 a1 = *reinterpret_cast<const f16x8*>(&X[(16 + r16) * 392 + ks * 32 + g4i * 8]);
            #pragma unroll
            for (int n = 0; n < 4; ++n) {
                f16x8 b = *reinterpret_cast<const f16x8*>(
                    &bw[((size_t)(ks * 16 + wv * 4 + n) * 64 + lane) * 8]);
                acc[0][n] = MFMA16(a0, b, acc[0][n]);
                acc[1][n] = MFMA16(a1, b, acc[1][n]);
            }
        }
        #pragma unroll
        for (int n = 0; n < 4; ++n) {
            int c = wv * 64 + n * 16 + r16;
            float bias = bfr(b0[c]);
            #pragma unroll
            for (int m = 0; m < 2; ++m)
                #pragma unroll
                for (int qi = 0; qi < 4; ++qi) {
                    int rr = m * 16 + g4i * 4 + qi;
                    H1[rr * 264 + c] = (f16_t)fmaxf(acc[m][n][qi] + bias, 0.f);
                }
        }
    }
    __syncthreads();

    // ---- layer 2: h1 @ ew1 -> h2 (stored in X region, stride 264)
    f16_t* h2 = X;
    {
        f32x4 acc[2][4] = {};
        const f16_t* bw = pw + 98304;               // ew1
        for (int ks = 0; ks < 8; ++ks) {
            f16x8 a0 = *reinterpret_cast<const f16x8*>(&H1[r16 * 264 + ks * 32 + g4i * 8]);
            f16x8 a1 = *reinterpret_cast<const f16x8*>(&H1[(16 + r16) * 264 + ks * 32 + g4i * 8]);
            #pragma unroll
            for (int n = 0; n < 4; ++n) {
                f16x8 b = *reinterpret_cast<const f16x8*>(
                    &bw[((size_t)(ks * 16 + wv * 4 + n) * 64 + lane) * 8]);
                acc[0][n] = MFMA16(a0, b, acc[0][n]);
                acc[1][n] = MFMA16(a1, b, acc[1][n]);
            }
        }
        // All waves are past the X-reads (layer-1 barrier); X region is free.
        #pragma unroll
        for (int n = 0; n < 4; ++n) {
            int c = wv * 64 + n * 16 + r16;
            float bias = bfr(b1[c]);
            #pragma unroll
            for (int m = 0; m < 2; ++m)
                #pragma unroll
                for (int qi = 0; qi < 4; ++qi) {
                    int rr = m * 16 + g4i * 4 + qi;
                    h2[rr * 264 + c] = (f16_t)fmaxf(acc[m][n][qi] + bias, 0.f);
                }
        }
    }
    __syncthreads();

    // ---- layer 3 + residual: relu(h2 @ ew2 + b2) + e @ eLin ; cols [wv*32,+32)
    {
        f32x4 accF[2][2] = {}, accR[2][2] = {};
        const f16_t* bw = pw + 163840;              // ew2 (NT=8)
        for (int ks = 0; ks < 8; ++ks) {
            f16x8 a0 = *reinterpret_cast<const f16x8*>(&h2[r16 * 264 + ks * 32 + g4i * 8]);
            f16x8 a1 = *reinterpret_cast<const f16x8*>(&h2[(16 + r16) * 264 + ks * 32 + g4i * 8]);
            #pragma unroll
            for (int n = 0; n < 2; ++n) {
                f16x8 b = *reinterpret_cast<const f16x8*>(
                    &bw[((size_t)(ks * 8 + wv * 2 + n) * 64 + lane) * 8]);
                accF[0][n] = MFMA16(a0, b, accF[0][n]);
                accF[1][n] = MFMA16(a1, b, accF[1][n]);
            }
        }
        const f16_t* bwL = pw + 196608;             // eLin (NT=8)
        for (int ks = 0; ks < 4; ++ks) {
            f16x8 a0 = *reinterpret_cast<const f16x8*>(&ER[r16 * 136 + ks * 32 + g4i * 8]);
            f16x8 a1 = *reinterpret_cast<const f16x8*>(&ER[(16 + r16) * 136 + ks * 32 + g4i * 8]);
            #pragma unroll
            for (int n = 0; n < 2; ++n) {
                f16x8 b = *reinterpret_cast<const f16x8*>(
                    &bwL[((size_t)(ks * 8 + wv * 2 + n) * 64 + lane) * 8]);
                accR[0][n] = MFMA16(a0, b, accR[0][n]);
                accR[1][n] = MFMA16(a1, b, accR[1][n]);
            }
        }
        #pragma unroll
        for (int n = 0; n < 2; ++n) {
            int c = wv * 32 + n * 16 + r16;
            float bias = bfr(b2[c]);
            #pragma unroll
            for (int m = 0; m < 2; ++m)
                #pragma unroll
                for (int qi = 0; qi < 4; ++qi) {
                    int rr = m * 16 + g4i * 4 + qi;
                    float val = accR[m][n][qi] + fmaxf(accF[m][n][qi] + bias, 0.f);
                    size_t eg2 = ebase + rr;
                    out_e[eg2 * 128 + c] = val;
                    unsafeAtomicAdd(&aggr[(size_t)cidx[rr] * 128 + c], val);
                }
        }
    }
}

// ---------------------------------------------------------------------------
// Node kernel: 32 nodes/block, 256 threads, 4 blocks/CU.
// node_in = [aggr/clip(cnt) (f32, derived) | bf16(v)]; f16 mids.
// ---------------------------------------------------------------------------
__launch_bounds__(256, 4)
__global__ void node_kernel(
    const float* __restrict__ vfeat, const float* __restrict__ aggr,
    const float* __restrict__ cnts,
    const float* __restrict__ lng, const float* __restrict__ lnb,
    const f16_t* __restrict__ pw,                   // node weight base (nw0)
    const float* __restrict__ b0, const float* __restrict__ b1,
    const float* __restrict__ b2,
    float* __restrict__ out_v, int Nn)
{
    __shared__ f16_t X[32 * 264];
    __shared__ f16_t H1[32 * 264];

    const int t    = threadIdx.x;
    const int lane = t & 63;
    const int wv   = t >> 6;
    const size_t nbase = (size_t)blockIdx.x * 32;

    const int nl = t >> 3;
    const int pp = t & 7;
    const size_t ng = nbase + nl;
    const bool valid = ng < (size_t)Nn;

    float4 d[8];
    float s = 0.f, sq = 0.f;
    {
        float cmax = 1.f;
        if (valid) cmax = fmaxf(cnts[ng], 1.f);
        const float4* a4 = (const float4*)aggr;
        const float4* v4 = (const float4*)vfeat;
        #pragma unroll
        for (int i = 0; i < 8; ++i) {
            int q = i * 8 + pp;                    // f4 index within 64 (=256 floats)
            float4 r = make_float4(0.f, 0.f, 0.f, 0.f);
            if (valid) {
                if (q < 32) {
                    r = a4[ng * 32 + q];
                    r.x = r.x / cmax; r.y = r.y / cmax;
                    r.z = r.z / cmax; r.w = r.w / cmax;   // f32, derived — not rounded
                } else {
                    float4 rv = v4[ng * 32 + (q - 32)];
                    r.x = bfr(rv.x); r.y = bfr(rv.y); r.z = bfr(rv.z); r.w = bfr(rv.w);
                }
            }
            d[i] = r;
            s  += r.x + r.y + r.z + r.w;
            sq += r.x*r.x + r.y*r.y + r.z*r.z + r.w*r.w;
        }
    }
    #pragma unroll
    for (int off = 1; off < 8; off <<= 1) {
        s  += __shfl_xor(s, off);
        sq += __shfl_xor(sq, off);
    }
    const float mean = s * (1.f / 256.f);
    const float rstd = 1.f / sqrtf(sq * (1.f / 256.f) - mean * mean + 1e-5f);
    {
        const float4* g4p = (const float4*)lng;
        const float4* bpp = (const float4*)lnb;
        #pragma unroll
        for (int i = 0; i < 8; ++i) {
            int q = i * 8 + pp;
            float4 g = g4p[q]; float4 bb = bpp[q];
            f16x4 y;
            y[0] = (f16_t)((d[i].x - mean) * rstd * bfr(g.x) + bfr(bb.x));
            y[1] = (f16_t)((d[i].y - mean) * rstd * bfr(g.y) + bfr(bb.y));
            y[2] = (f16_t)((d[i].z - mean) * rstd * bfr(g.z) + bfr(bb.z));
            y[3] = (f16_t)((d[i].w - mean) * rstd * bfr(g.w) + bfr(bb.w));
            *reinterpret_cast<f16x4*>(&X[nl * 264 + q * 4]) = y;
        }
    }
    __syncthreads();

    const int r16 = lane & 15;
    const int g4i = lane >> 4;

    // ---- layer 1: x[32,256] @ nw0 -> h1
    {
        f32x4 acc[2][4] = {};
        const f16_t* bw = pw;                       // nw0
        for (int ks = 0; ks < 8; ++ks) {
            f16x8 a0 = *reinterpret_cast<const f16x8*>(&X[r16 * 264 + ks * 32 + g4i * 8]);
            f16x8 a1 = *reinterpret_cast<const f16x8*>(&X[(16 + r16) * 264 + ks * 32 + g4i * 8]);
            #pragma unroll
            for (int n = 0; n < 4; ++n) {
                f16x8 b = *reinterpret_cast<const f16x8*>(
                    &bw[((size_t)(ks * 16 + wv * 4 + n) * 64 + lane) * 8]);
                acc[0][n] = MFMA16(a0, b, acc[0][n]);
                acc[1][n] = MFMA16(a1, b, acc[1][n]);
            }
        }
        #pragma unroll
        for (int n = 0; n < 4; ++n) {
            int c = wv * 64 + n * 16 + r16;
            float bias = bfr(b0[c]);
            #pragma unroll
            for (int m = 0; m < 2; ++m)
                #pragma unroll
                for (int qi = 0; qi < 4; ++qi) {
                    int rr = m * 16 + g4i * 4 + qi;
                    H1[rr * 264 + c] = (f16_t)fmaxf(acc[m][n][qi] + bias, 0.f);
                }
        }
    }
    __syncthreads();

    // ---- layer 2: h1 @ nw1 -> h2 (X region)
    f16_t* h2 = X;
    {
        f32x4 acc[2][4] = {};
        const f16_t* bw = pw + 65536;               // nw1
        for (int ks = 0; ks < 8; ++ks) {
            f16x8 a0 = *reinterpret_cast<const f16x8*>(&H1[r16 * 264 + ks * 32 + g4i * 8]);
            f16x8 a1 = *reinterpret_cast<const f16x8*>(&H1[(16 + r16) * 264 + ks * 32 + g4i * 8]);
            #pragma unroll
            for (int n = 0; n < 4; ++n) {
                f16x8 b = *reinterpret_cast<const f16x8*>(
                    &bw[((size_t)(ks * 16 + wv * 4 + n) * 64 + lane) * 8]);
                acc[0][n] = MFMA16(a0, b, acc[0][n]);
                acc[1][n] = MFMA16(a1, b, acc[1][n]);
            }
        }
        #pragma unroll
        for (int n = 0; n < 4; ++n) {
            int c = wv * 64 + n * 16 + r16;
            float bias = bfr(b1[c]);
            #pragma unroll
            for (int m = 0; m < 2; ++m)
                #pragma unroll
                for (int qi = 0; qi < 4; ++qi) {
                    int rr = m * 16 + g4i * 4 + qi;
                    h2[rr * 264 + c] = (f16_t)fmaxf(acc[m][n][qi] + bias, 0.f);
                }
        }
    }
    __syncthreads();

    // ---- layer 3 + residual: relu(h2 @ nw2 + b2) + v @ nLin
    {
        f32x4 accF[2][2] = {}, accR[2][2] = {};
        const f16_t* bw = pw + 131072;              // nw2 (NT=8)
        for (int ks = 0; ks < 8; ++ks) {
            f16x8 a0 = *reinterpret_cast<const f16x8*>(&h2[r16 * 264 + ks * 32 + g4i * 8]);
            f16x8 a1 = *reinterpret_cast<const f16x8*>(&h2[(16 + r16) * 264 + ks * 32 + g4i * 8]);
            #pragma unroll
            for (int n = 0; n < 2; ++n) {
                f16x8 b = *reinterpret_cast<const f16x8*>(
                    &bw[((size_t)(ks * 8 + wv * 2 + n) * 64 + lane) * 8]);
                accF[0][n] = MFMA16(a0, b, accF[0][n]);
                accF[1][n] = MFMA16(a1, b, accF[1][n]);
            }
        }
        const f16_t* bwL = pw + 163840;             // nLin (NT=8)
        for (int ks = 0; ks < 4; ++ks) {
            f16x8 a[2];
            #pragma unroll
            for (int m = 0; m < 2; ++m) {
                size_t rv = nbase + (size_t)(m * 16 + r16);
                if (rv >= (size_t)Nn) rv = (size_t)Nn - 1;   // clamp (rows unused)
                const float* src = &vfeat[rv * 128 + ks * 32 + g4i * 8];
                float4 f0 = *(const float4*)src;
                float4 f1 = *(const float4*)(src + 4);
                f16x8 av;
                av[0] = (f16_t)bfr(f0.x); av[1] = (f16_t)bfr(f0.y);
                av[2] = (f16_t)bfr(f0.z); av[3] = (f16_t)bfr(f0.w);
                av[4] = (f16_t)bfr(f1.x); av[5] = (f16_t)bfr(f1.y);
                av[6] = (f16_t)bfr(f1.z); av[7] = (f16_t)bfr(f1.w);
                a[m] = av;
            }
            #pragma unroll
            for (int n = 0; n < 2; ++n) {
                f16x8 b = *reinterpret_cast<const f16x8*>(
                    &bwL[((size_t)(ks * 8 + wv * 2 + n) * 64 + lane) * 8]);
                accR[0][n] = MFMA16(a[0], b, accR[0][n]);
                accR[1][n] = MFMA16(a[1], b, accR[1][n]);
            }
        }
        #pragma unroll
        for (int n = 0; n < 2; ++n) {
            int c = wv * 32 + n * 16 + r16;
            float bias = bfr(b2[c]);
            #pragma unroll
            for (int m = 0; m < 2; ++m)
                #pragma unroll
                for (int qi = 0; qi < 4; ++qi) {
                    int rr = m * 16 + g4i * 4 + qi;
                    size_t ng2 = nbase + rr;
                    if (ng2 < (size_t)Nn) {
                        float val = accR[m][n][qi] + fmaxf(accF[m][n][qi] + bias, 0.f);
                        out_v[ng2 * 128 + c] = val;
                    }
                }
        }
    }
}

// ---------------------------------------------------------------------------
extern "C" void kernel_launch(void* const* d_in, const int* in_sizes, int n_in,
                              void* d_out, int out_size, void* d_ws, size_t ws_size,
                              hipStream_t stream)
{
    const float* v    = (const float*)d_in[0];
    const float* e    = (const float*)d_in[1];
    const int*   eidx = (const int*)d_in[2];
    const float* elng = (const float*)d_in[3];
    const float* elnb = (const float*)d_in[4];
    const float* ew0  = (const float*)d_in[5];
    const float* eb0  = (const float*)d_in[6];
    const float* ew1  = (const float*)d_in[7];
    const float* eb1  = (const float*)d_in[8];
    const float* ew2  = (const float*)d_in[9];
    const float* eb2  = (const float*)d_in[10];
    const float* eLin = (const float*)d_in[11];
    const float* nlng = (const float*)d_in[12];
    const float* nlnb = (const float*)d_in[13];
    const float* nw0  = (const float*)d_in[14];
    const float* nb0  = (const float*)d_in[15];
    const float* nw1  = (const float*)d_in[16];
    const float* nb1  = (const float*)d_in[17];
    const float* nw2  = (const float*)d_in[18];
    const float* nb2  = (const float*)d_in[19];
    const float* nLin = (const float*)d_in[20];

    const int Nn = in_sizes[0] / 128;
    const int Ee = in_sizes[1] / 128;

    float* out_v = (float*)d_out;
    float* out_e = out_v + (size_t)Nn * 128;

    float* aggr = (float*)d_ws;                       // [Nn][128] f32
    float* cnts = aggr + (size_t)Nn * 128;            // [Nn] f32
    f16_t* packw = (f16_t*)((char*)d_ws + (size_t)Nn * 129 * 4);  // 393216 f16

    hipMemsetAsync(d_ws, 0, (size_t)Nn * 129 * 4, stream);

    pack_weights_kernel<<<192, 256, 0, stream>>>(ew0, ew1, ew2, eLin,
                                                 nw0, nw1, nw2, nLin, packw);

    edge_kernel<<<Ee / 32, 256, 0, stream>>>(v, e, eidx, elng, elnb, packw,
                                             eb0, eb1, eb2, out_e, aggr, cnts, Ee);

    node_kernel<<<(Nn + 31) / 32, 256, 0, stream>>>(v, aggr, cnts, nlng, nlnb,
                                                    packw + 212992, nb0, nb1, nb2,
                                                    out_v, Nn);
}

// Round 5
// 453.503 us; speedup vs baseline: 2.1156x; 1.0324x over previous
//
#include <hip/hip_runtime.h>

typedef _Float16 f16_t;
typedef f16_t f16x4 __attribute__((ext_vector_type(4)));
typedef f16_t f16x8 __attribute__((ext_vector_type(8)));
typedef float f32x4 __attribute__((ext_vector_type(4)));

#define MFMA16(a, b, c) __builtin_amdgcn_mfma_f32_16x16x32_f16((a), (b), (c), 0, 0, 0)

// bf16 round (RNE) of an f32 — matches the reference harness's input rounding.
// bf16 values at these magnitudes are exactly representable in f16.
__device__ __forceinline__ float bfr(float x) { return (float)(__bf16)x; }

// ---------------------------------------------------------------------------
// Pack fp32 weight matrices into f16 MFMA B-fragment order, bf16-rounded.
// B-frag (kstep, ntile): lane l, elem j -> W[kstep*32 + (l>>4)*8 + j][ntile*16 + (l&15)]
// stored at dst[doff + ((kstep*NT + ntile)*64 + l)*8 + j]
// ---------------------------------------------------------------------------
__global__ void pack_weights_kernel(
    const float* __restrict__ ew0, const float* __restrict__ ew1,
    const float* __restrict__ ew2, const float* __restrict__ eL,
    const float* __restrict__ nw0, const float* __restrict__ nw1,
    const float* __restrict__ nw2, const float* __restrict__ nL,
    f16_t* __restrict__ dst)
{
    int tid = blockIdx.x * 256 + threadIdx.x;
    int fid = tid >> 6, lane = tid & 63;
    const float* src; int Ncols, foff, doff;
    if (fid < 192)      { src = ew0; Ncols = 256; foff = 0;   doff = 0;      }
    else if (fid < 320) { src = ew1; Ncols = 256; foff = 192; doff = 98304;  }
    else if (fid < 384) { src = ew2; Ncols = 128; foff = 320; doff = 163840; }
    else if (fid < 416) { src = eL;  Ncols = 128; foff = 384; doff = 196608; }
    else if (fid < 544) { src = nw0; Ncols = 256; foff = 416; doff = 212992; }
    else if (fid < 672) { src = nw1; Ncols = 256; foff = 544; doff = 278528; }
    else if (fid < 736) { src = nw2; Ncols = 128; foff = 672; doff = 344064; }
    else                { src = nL;  Ncols = 128; foff = 736; doff = 376832; }
    int f = fid - foff;
    int NT = Ncols >> 4;
    int kstep = f / NT, ntile = f - kstep * NT;
    int col = ntile * 16 + (lane & 15);
    int kbase = kstep * 32 + ((lane >> 4) << 3);
    f16x8 out;
    #pragma unroll
    for (int j = 0; j < 8; ++j)
        out[j] = (f16_t)bfr(src[(size_t)(kbase + j) * Ncols + col]);
    *reinterpret_cast<f16x8*>(dst + (size_t)doff + ((size_t)f * 64 + lane) * 8) = out;
}

// ---------------------------------------------------------------------------
// Edge kernel: 32 edges/block, 512 threads (8 waves), 3 blocks/CU (LDS-capped)
// -> 24 waves/CU. Inputs bf16-rounded; f16 mids; f32 accumulation.
// LDS: X [32][392] (LN'd concat; reused as h2 w/ stride 264), H1 [32][264],
//      ER [32][136] (raw bf16 e for the residual matmul).
// ---------------------------------------------------------------------------
__launch_bounds__(512, 6)
__global__ void edge_kernel(
    const float* __restrict__ vfeat, const float* __restrict__ efeat,
    const int* __restrict__ eidx,
    const float* __restrict__ lng, const float* __restrict__ lnb,
    const f16_t* __restrict__ pw,
    const float* __restrict__ b0, const float* __restrict__ b1,
    const float* __restrict__ b2,
    float* __restrict__ out_e, float* __restrict__ aggr, float* __restrict__ cnts,
    int Ee)
{
    __shared__ f16_t X[32 * 392];
    __shared__ f16_t H1[32 * 264];
    __shared__ f16_t ER[32 * 136];
    __shared__ int cidx[32];

    const int t    = threadIdx.x;
    const int lane = t & 63;
    const int wv   = t >> 6;          // 0..7
    const size_t ebase = (size_t)blockIdx.x * 32;

    // ---- phase 0: gather + bf16-round (keep in regs) + LN stats + stage raw e
    // thread (el, pp): pp-th of 16 slices of one edge row (6 float4 each)
    const int el = t >> 4;
    const int pp = t & 15;
    const size_t eg = ebase + el;
    const int r0 = eidx[eg];
    const int c0 = eidx[(size_t)Ee + eg];

    float4 d[6];
    float s = 0.f, sq = 0.f;
    {
        const float4* e4 = (const float4*)efeat;
        const float4* v4 = (const float4*)vfeat;
        #pragma unroll
        for (int i = 0; i < 6; ++i) {
            int q = i * 16 + pp;                // f4 index within 96 (=384 floats)
            float4 r;
            if (q < 32)      r = e4[eg * 32 + q];
            else if (q < 64) r = v4[(size_t)r0 * 32 + (q - 32)];
            else             r = v4[(size_t)c0 * 32 + (q - 64)];
            d[i].x = bfr(r.x); d[i].y = bfr(r.y); d[i].z = bfr(r.z); d[i].w = bfr(r.w);
            if (q < 32) {
                f16x4 ev;
                ev[0] = (f16_t)d[i].x; ev[1] = (f16_t)d[i].y;
                ev[2] = (f16_t)d[i].z; ev[3] = (f16_t)d[i].w;
                *reinterpret_cast<f16x4*>(&ER[el * 136 + q * 4]) = ev;
            }
            s  += d[i].x + d[i].y + d[i].z + d[i].w;
            sq += d[i].x*d[i].x + d[i].y*d[i].y + d[i].z*d[i].z + d[i].w*d[i].w;
        }
        if (pp == 0) {
            cidx[el] = c0;
            unsafeAtomicAdd(&cnts[c0], 1.0f);
        }
    }
    #pragma unroll
    for (int off = 1; off < 16; off <<= 1) {
        s  += __shfl_xor(s, off);
        sq += __shfl_xor(sq, off);
    }
    const float mean = s * (1.f / 384.f);
    const float rstd = 1.f / sqrtf(sq * (1.f / 384.f) - mean * mean + 1e-5f);

    // ---- phase 1: normalize in f32, store f16 to LDS
    {
        const float4* g4p = (const float4*)lng;
        const float4* bpp = (const float4*)lnb;
        #pragma unroll
        for (int i = 0; i < 6; ++i) {
            int q = i * 16 + pp;
            float4 g = g4p[q]; float4 bb = bpp[q];
            f16x4 y;
            y[0] = (f16_t)((d[i].x - mean) * rstd * bfr(g.x) + bfr(bb.x));
            y[1] = (f16_t)((d[i].y - mean) * rstd * bfr(g.y) + bfr(bb.y));
            y[2] = (f16_t)((d[i].z - mean) * rstd * bfr(g.z) + bfr(bb.z));
            y[3] = (f16_t)((d[i].w - mean) * rstd * bfr(g.w) + bfr(bb.w));
            *reinterpret_cast<f16x4*>(&X[el * 392 + q * 4]) = y;
        }
    }
    __syncthreads();

    const int r16 = lane & 15;
    const int g4i = lane >> 4;

    // ---- layer 1: x[32,384] @ ew0 -> h1[32,256]; wave wv covers cols [wv*32,+32)
    {
        f32x4 acc[2][2] = {};
        const f16_t* bw = pw;                       // ew0 (NT=16)
        #pragma unroll
        for (int ks = 0; ks < 12; ++ks) {
            f16x8 a0 = *reinterpret_cast<const f16x8*>(&X[r16 * 392 + ks * 32 + g4i * 8]);
            f16x8 a1 = *reinterpret_cast<const f16x8*>(&X[(16 + r16) * 392 + ks * 32 + g4i * 8]);
            #pragma unroll
            for (int n = 0; n < 2; ++n) {
                f16x8 b = *reinterpret_cast<const f16x8*>(
                    &bw[((size_t)(ks * 16 + wv * 2 + n) * 64 + lane) * 8]);
                acc[0][n] = MFMA16(a0, b, acc[0][n]);
                acc[1][n] = MFMA16(a1, b, acc[1][n]);
            }
        }
        #pragma unroll
        for (int n = 0; n < 2; ++n) {
            int c = wv * 32 + n * 16 + r16;
            float bias = bfr(b0[c]);
            #pragma unroll
            for (int m = 0; m < 2; ++m)
                #pragma unroll
                for (int qi = 0; qi < 4; ++qi) {
                    int rr = m * 16 + g4i * 4 + qi;
                    H1[rr * 264 + c] = (f16_t)fmaxf(acc[m][n][qi] + bias, 0.f);
                }
        }
    }
    __syncthreads();

    // ---- layer 2: h1 @ ew1 -> h2 (stored in X region, stride 264)
    f16_t* h2 = X;
    {
        f32x4 acc[2][2] = {};
        const f16_t* bw = pw + 98304;               // ew1 (NT=16)
        #pragma unroll
        for (int ks = 0; ks < 8; ++ks) {
            f16x8 a0 = *reinterpret_cast<const f16x8*>(&H1[r16 * 264 + ks * 32 + g4i * 8]);
            f16x8 a1 = *reinterpret_cast<const f16x8*>(&H1[(16 + r16) * 264 + ks * 32 + g4i * 8]);
            #pragma unroll
            for (int n = 0; n < 2; ++n) {
                f16x8 b = *reinterpret_cast<const f16x8*>(
                    &bw[((size_t)(ks * 16 + wv * 2 + n) * 64 + lane) * 8]);
                acc[0][n] = MFMA16(a0, b, acc[0][n]);
                acc[1][n] = MFMA16(a1, b, acc[1][n]);
            }
        }
        // All waves are past the X-reads (layer-1 barrier); X region is free.
        #pragma unroll
        for (int n = 0; n < 2; ++n) {
            int c = wv * 32 + n * 16 + r16;
            float bias = bfr(b1[c]);
            #pragma unroll
            for (int m = 0; m < 2; ++m)
                #pragma unroll
                for (int qi = 0; qi < 4; ++qi) {
                    int rr = m * 16 + g4i * 4 + qi;
                    h2[rr * 264 + c] = (f16_t)fmaxf(acc[m][n][qi] + bias, 0.f);
                }
        }
    }
    __syncthreads();

    // ---- layer 3 + residual: relu(h2 @ ew2 + b2) + e @ eLin ; wave covers cols [wv*16,+16)
    {
        f32x4 accF[2] = {}, accR[2] = {};
        const f16_t* bw = pw + 163840;              // ew2 (NT=8)
        #pragma unroll
        for (int ks = 0; ks < 8; ++ks) {
            f16x8 a0 = *reinterpret_cast<const f16x8*>(&h2[r16 * 264 + ks * 32 + g4i * 8]);
            f16x8 a1 = *reinterpret_cast<const f16x8*>(&h2[(16 + r16) * 264 + ks * 32 + g4i * 8]);
            f16x8 b = *reinterpret_cast<const f16x8*>(
                &bw[((size_t)(ks * 8 + wv) * 64 + lane) * 8]);
            accF[0] = MFMA16(a0, b, accF[0]);
            accF[1] = MFMA16(a1, b, accF[1]);
        }
        const f16_t* bwL = pw + 196608;             // eLin (NT=8)
        #pragma unroll
        for (int ks = 0; ks < 4; ++ks) {
            f16x8 a0 = *reinterpret_cast<const f16x8*>(&ER[r16 * 136 + ks * 32 + g4i * 8]);
            f16x8 a1 = *reinterpret_cast<const f16x8*>(&ER[(16 + r16) * 136 + ks * 32 + g4i * 8]);
            f16x8 b = *reinterpret_cast<const f16x8*>(
                &bwL[((size_t)(ks * 8 + wv) * 64 + lane) * 8]);
            accR[0] = MFMA16(a0, b, accR[0]);
            accR[1] = MFMA16(a1, b, accR[1]);
        }
        int c = wv * 16 + r16;
        float bias = bfr(b2[c]);
        #pragma unroll
        for (int m = 0; m < 2; ++m)
            #pragma unroll
            for (int qi = 0; qi < 4; ++qi) {
                int rr = m * 16 + g4i * 4 + qi;
                float val = accR[m][qi] + fmaxf(accF[m][qi] + bias, 0.f);
                size_t eg2 = ebase + rr;
                out_e[eg2 * 128 + c] = val;
                unsafeAtomicAdd(&aggr[(size_t)cidx[rr] * 128 + c], val);
            }
    }
}

// ---------------------------------------------------------------------------
// Node kernel: 32 nodes/block, 512 threads (8 waves), ~4 blocks/CU (33 KB LDS).
// node_in = [aggr/clip(cnt) (f32, derived) | bf16(v)]; f16 mids.
// ---------------------------------------------------------------------------
__launch_bounds__(512, 6)
__global__ void node_kernel(
    const float* __restrict__ vfeat, const float* __restrict__ aggr,
    const float* __restrict__ cnts,
    const float* __restrict__ lng, const float* __restrict__ lnb,
    const f16_t* __restrict__ pw,                   // node weight base (nw0)
    const float* __restrict__ b0, const float* __restrict__ b1,
    const float* __restrict__ b2,
    float* __restrict__ out_v, int Nn)
{
    __shared__ f16_t X[32 * 264];
    __shared__ f16_t H1[32 * 264];

    const int t    = threadIdx.x;
    const int lane = t & 63;
    const int wv   = t >> 6;
    const size_t nbase = (size_t)blockIdx.x * 32;

    const int nl = t >> 4;
    const int pp = t & 15;
    const size_t ng = nbase + nl;
    const bool valid = ng < (size_t)Nn;

    float4 d[4];
    float s = 0.f, sq = 0.f;
    {
        float cmax = 1.f;
        if (valid) cmax = fmaxf(cnts[ng], 1.f);
        const float4* a4 = (const float4*)aggr;
        const float4* v4 = (const float4*)vfeat;
        #pragma unroll
        for (int i = 0; i < 4; ++i) {
            int q = i * 16 + pp;                   // f4 index within 64 (=256 floats)
            float4 r = make_float4(0.f, 0.f, 0.f, 0.f);
            if (valid) {
                if (q < 32) {
                    r = a4[ng * 32 + q];
                    r.x = r.x / cmax; r.y = r.y / cmax;
                    r.z = r.z / cmax; r.w = r.w / cmax;   // f32, derived — not rounded
                } else {
                    float4 rv = v4[ng * 32 + (q - 32)];
                    r.x = bfr(rv.x); r.y = bfr(rv.y); r.z = bfr(rv.z); r.w = bfr(rv.w);
                }
            }
            d[i] = r;
            s  += r.x + r.y + r.z + r.w;
            sq += r.x*r.x + r.y*r.y + r.z*r.z + r.w*r.w;
        }
    }
    #pragma unroll
    for (int off = 1; off < 16; off <<= 1) {
        s  += __shfl_xor(s, off);
        sq += __shfl_xor(sq, off);
    }
    const float mean = s * (1.f / 256.f);
    const float rstd = 1.f / sqrtf(sq * (1.f / 256.f) - mean * mean + 1e-5f);
    {
        const float4* g4p = (const float4*)lng;
        const float4* bpp = (const float4*)lnb;
        #pragma unroll
        for (int i = 0; i < 4; ++i) {
            int q = i * 16 + pp;
            float4 g = g4p[q]; float4 bb = bpp[q];
            f16x4 y;
            y[0] = (f16_t)((d[i].x - mean) * rstd * bfr(g.x) + bfr(bb.x));
            y[1] = (f16_t)((d[i].y - mean) * rstd * bfr(g.y) + bfr(bb.y));
            y[2] = (f16_t)((d[i].z - mean) * rstd * bfr(g.z) + bfr(bb.z));
            y[3] = (f16_t)((d[i].w - mean) * rstd * bfr(g.w) + bfr(bb.w));
            *reinterpret_cast<f16x4*>(&X[nl * 264 + q * 4]) = y;
        }
    }
    __syncthreads();

    const int r16 = lane & 15;
    const int g4i = lane >> 4;

    // ---- layer 1: x[32,256] @ nw0 -> h1; wave covers cols [wv*32,+32)
    {
        f32x4 acc[2][2] = {};
        const f16_t* bw = pw;                       // nw0 (NT=16)
        #pragma unroll
        for (int ks = 0; ks < 8; ++ks) {
            f16x8 a0 = *reinterpret_cast<const f16x8*>(&X[r16 * 264 + ks * 32 + g4i * 8]);
            f16x8 a1 = *reinterpret_cast<const f16x8*>(&X[(16 + r16) * 264 + ks * 32 + g4i * 8]);
            #pragma unroll
            for (int n = 0; n < 2; ++n) {
                f16x8 b = *reinterpret_cast<const f16x8*>(
                    &bw[((size_t)(ks * 16 + wv * 2 + n) * 64 + lane) * 8]);
                acc[0][n] = MFMA16(a0, b, acc[0][n]);
                acc[1][n] = MFMA16(a1, b, acc[1][n]);
            }
        }
        #pragma unroll
        for (int n = 0; n < 2; ++n) {
            int c = wv * 32 + n * 16 + r16;
            float bias = bfr(b0[c]);
            #pragma unroll
            for (int m = 0; m < 2; ++m)
                #pragma unroll
                for (int qi = 0; qi < 4; ++qi) {
                    int rr = m * 16 + g4i * 4 + qi;
                    H1[rr * 264 + c] = (f16_t)fmaxf(acc[m][n][qi] + bias, 0.f);
                }
        }
    }
    __syncthreads();

    // ---- layer 2: h1 @ nw1 -> h2 (X region)
    f16_t* h2 = X;
    {
        f32x4 acc[2][2] = {};
        const f16_t* bw = pw + 65536;               // nw1 (NT=16)
        #pragma unroll
        for (int ks = 0; ks < 8; ++ks) {
            f16x8 a0 = *reinterpret_cast<const f16x8*>(&H1[r16 * 264 + ks * 32 + g4i * 8]);
            f16x8 a1 = *reinterpret_cast<const f16x8*>(&H1[(16 + r16) * 264 + ks * 32 + g4i * 8]);
            #pragma unroll
            for (int n = 0; n < 2; ++n) {
                f16x8 b = *reinterpret_cast<const f16x8*>(
                    &bw[((size_t)(ks * 16 + wv * 2 + n) * 64 + lane) * 8]);
                acc[0][n] = MFMA16(a0, b, acc[0][n]);
                acc[1][n] = MFMA16(a1, b, acc[1][n]);
            }
        }
        #pragma unroll
        for (int n = 0; n < 2; ++n) {
            int c = wv * 32 + n * 16 + r16;
            float bias = bfr(b1[c]);
            #pragma unroll
            for (int m = 0; m < 2; ++m)
                #pragma unroll
                for (int qi = 0; qi < 4; ++qi) {
                    int rr = m * 16 + g4i * 4 + qi;
                    h2[rr * 264 + c] = (f16_t)fmaxf(acc[m][n][qi] + bias, 0.f);
                }
        }
    }
    __syncthreads();

    // ---- layer 3 + residual: relu(h2 @ nw2 + b2) + v @ nLin ; cols [wv*16,+16)
    {
        f32x4 accF[2] = {}, accR[2] = {};
        const f16_t* bw = pw + 131072;              // nw2 (NT=8)
        #pragma unroll
        for (int ks = 0; ks < 8; ++ks) {
            f16x8 a0 = *reinterpret_cast<const f16x8*>(&h2[r16 * 264 + ks * 32 + g4i * 8]);
            f16x8 a1 = *reinterpret_cast<const f16x8*>(&h2[(16 + r16) * 264 + ks * 32 + g4i * 8]);
            f16x8 b = *reinterpret_cast<const f16x8*>(
                &bw[((size_t)(ks * 8 + wv) * 64 + lane) * 8]);
            accF[0] = MFMA16(a0, b, accF[0]);
            accF[1] = MFMA16(a1, b, accF[1]);
        }
        const f16_t* bwL = pw + 163840;             // nLin (NT=8)
        #pragma unroll
        for (int ks = 0; ks < 4; ++ks) {
            f16x8 a[2];
            #pragma unroll
            for (int m = 0; m < 2; ++m) {
                size_t rv = nbase + (size_t)(m * 16 + r16);
                if (rv >= (size_t)Nn) rv = (size_t)Nn - 1;   // clamp (rows unused)
                const float* src = &vfeat[rv * 128 + ks * 32 + g4i * 8];
                float4 f0 = *(const float4*)src;
                float4 f1 = *(const float4*)(src + 4);
                f16x8 av;
                av[0] = (f16_t)bfr(f0.x); av[1] = (f16_t)bfr(f0.y);
                av[2] = (f16_t)bfr(f0.z); av[3] = (f16_t)bfr(f0.w);
                av[4] = (f16_t)bfr(f1.x); av[5] = (f16_t)bfr(f1.y);
                av[6] = (f16_t)bfr(f1.z); av[7] = (f16_t)bfr(f1.w);
                a[m] = av;
            }
            f16x8 b = *reinterpret_cast<const f16x8*>(
                &bwL[((size_t)(ks * 8 + wv) * 64 + lane) * 8]);
            accR[0] = MFMA16(a[0], b, accR[0]);
            accR[1] = MFMA16(a[1], b, accR[1]);
        }
        int c = wv * 16 + r16;
        float bias = bfr(b2[c]);
        #pragma unroll
        for (int m = 0; m < 2; ++m)
            #pragma unroll
            for (int qi = 0; qi < 4; ++qi) {
                int rr = m * 16 + g4i * 4 + qi;
                size_t ng2 = nbase + rr;
                if (ng2 < (size_t)Nn) {
                    float val = accR[m][qi] + fmaxf(accF[m][qi] + bias, 0.f);
                    out_v[ng2 * 128 + c] = val;
                }
            }
    }
}

// ---------------------------------------------------------------------------
extern "C" void kernel_launch(void* const* d_in, const int* in_sizes, int n_in,
                              void* d_out, int out_size, void* d_ws, size_t ws_size,
                              hipStream_t stream)
{
    const float* v    = (const float*)d_in[0];
    const float* e    = (const float*)d_in[1];
    const int*   eidx = (const int*)d_in[2];
    const float* elng = (const float*)d_in[3];
    const float* elnb = (const float*)d_in[4];
    const float* ew0  = (const float*)d_in[5];
    const float* eb0  = (const float*)d_in[6];
    const float* ew1  = (const float*)d_in[7];
    const float* eb1  = (const float*)d_in[8];
    const float* ew2  = (const float*)d_in[9];
    const float* eb2  = (const float*)d_in[10];
    const float* eLin = (const float*)d_in[11];
    const float* nlng = (const float*)d_in[12];
    const float* nlnb = (const float*)d_in[13];
    const float* nw0  = (const float*)d_in[14];
    const float* nb0  = (const float*)d_in[15];
    const float* nw1  = (const float*)d_in[16];
    const float* nb1  = (const float*)d_in[17];
    const float* nw2  = (const float*)d_in[18];
    const float* nb2  = (const float*)d_in[19];
    const float* nLin = (const float*)d_in[20];

    const int Nn = in_sizes[0] / 128;
    const int Ee = in_sizes[1] / 128;

    float* out_v = (float*)d_out;
    float* out_e = out_v + (size_t)Nn * 128;

    float* aggr = (float*)d_ws;                       // [Nn][128] f32
    float* cnts = aggr + (size_t)Nn * 128;            // [Nn] f32
    f16_t* packw = (f16_t*)((char*)d_ws + (size_t)Nn * 129 * 4);  // 393216 f16

    hipMemsetAsync(d_ws, 0, (size_t)Nn * 129 * 4, stream);

    pack_weights_kernel<<<192, 256, 0, stream>>>(ew0, ew1, ew2, eLin,
                                                 nw0, nw1, nw2, nLin, packw);

    edge_kernel<<<Ee / 32, 512, 0, stream>>>(v, e, eidx, elng, elnb, packw,
                                             eb0, eb1, eb2, out_e, aggr, cnts, Ee);

    node_kernel<<<(Nn + 31) / 32, 512, 0, stream>>>(v, aggr, cnts, nlng, nlnb,
                                                    packw + 212992, nb0, nb1, nb2,
                                                    out_v, Nn);
}

// Round 6
// 436.030 us; speedup vs baseline: 2.2004x; 1.0401x over previous
//
#include <hip/hip_runtime.h>

typedef _Float16 f16_t;
typedef f16_t f16x4 __attribute__((ext_vector_type(4)));
typedef f16_t f16x8 __attribute__((ext_vector_type(8)));
typedef float f32x4 __attribute__((ext_vector_type(4)));

#define MFMA16(a, b, c) __builtin_amdgcn_mfma_f32_16x16x32_f16((a), (b), (c), 0, 0, 0)

// bf16 round (RNE) of an f32 — matches the reference harness's input rounding.
// bf16 values at these magnitudes are exactly representable in f16.
__device__ __forceinline__ float bfr(float x) { return (float)(__bf16)x; }

// ---------------------------------------------------------------------------
// Pack fp32 weight matrices into f16 MFMA B-fragment order, bf16-rounded.
// B-frag (kstep, ntile): lane l, elem j -> W[kstep*32 + (l>>4)*8 + j][ntile*16 + (l&15)]
// stored at dst[doff + ((kstep*NT + ntile)*64 + l)*8 + j]
// ---------------------------------------------------------------------------
__global__ void pack_weights_kernel(
    const float* __restrict__ ew0, const float* __restrict__ ew1,
    const float* __restrict__ ew2, const float* __restrict__ eL,
    const float* __restrict__ nw0, const float* __restrict__ nw1,
    const float* __restrict__ nw2, const float* __restrict__ nL,
    f16_t* __restrict__ dst)
{
    int tid = blockIdx.x * 256 + threadIdx.x;
    int fid = tid >> 6, lane = tid & 63;
    const float* src; int Ncols, foff, doff;
    if (fid < 192)      { src = ew0; Ncols = 256; foff = 0;   doff = 0;      }
    else if (fid < 320) { src = ew1; Ncols = 256; foff = 192; doff = 98304;  }
    else if (fid < 384) { src = ew2; Ncols = 128; foff = 320; doff = 163840; }
    else if (fid < 416) { src = eL;  Ncols = 128; foff = 384; doff = 196608; }
    else if (fid < 544) { src = nw0; Ncols = 256; foff = 416; doff = 212992; }
    else if (fid < 672) { src = nw1; Ncols = 256; foff = 544; doff = 278528; }
    else if (fid < 736) { src = nw2; Ncols = 128; foff = 672; doff = 344064; }
    else                { src = nL;  Ncols = 128; foff = 736; doff = 376832; }
    int f = fid - foff;
    int NT = Ncols >> 4;
    int kstep = f / NT, ntile = f - kstep * NT;
    int col = ntile * 16 + (lane & 15);
    int kbase = kstep * 32 + ((lane >> 4) << 3);
    f16x8 out;
    #pragma unroll
    for (int j = 0; j < 8; ++j)
        out[j] = (f16_t)bfr(src[(size_t)(kbase + j) * Ncols + col]);
    *reinterpret_cast<f16x8*>(dst + (size_t)doff + ((size_t)f * 64 + lane) * 8) = out;
}

// ---------------------------------------------------------------------------
// Edge kernel: 64 edges/block, 1024 threads (16 waves), 2 blocks/CU.
// Single LDS X buffer reused: LN'd concat (stride 392) -> H1 (stride 264)
// -> h2 (stride 264), with barriers between last-read and overwrite.
// ER holds raw bf16 e for the residual matmul. Weight B-frags stream from L2.
// ---------------------------------------------------------------------------
__launch_bounds__(1024, 8)
__global__ void edge_kernel(
    const float* __restrict__ vfeat, const float* __restrict__ efeat,
    const int* __restrict__ eidx,
    const float* __restrict__ lng, const float* __restrict__ lnb,
    const f16_t* __restrict__ pw,
    const float* __restrict__ b0, const float* __restrict__ b1,
    const float* __restrict__ b2,
    float* __restrict__ out_e, float* __restrict__ aggr, float* __restrict__ cnts,
    int Ee)
{
    __shared__ f16_t X[64 * 392];      // 50176 B, reused across layers
    __shared__ f16_t ER[64 * 136];     // 17408 B
    __shared__ int cidx[64];

    const int t    = threadIdx.x;
    const int lane = t & 63;
    const int wv   = t >> 6;           // 0..15
    const size_t ebase = (size_t)blockIdx.x * 64;

    // ---- phase 0: gather + bf16-round -> f16 LDS + LN stats
    // thread (el, pp): pp-th of 16 slices of one edge row (6 float4 each)
    const int el = t >> 4;             // 0..63
    const int pp = t & 15;
    const size_t eg = ebase + el;
    const int r0 = eidx[eg];
    const int c0 = eidx[(size_t)Ee + eg];

    float s = 0.f, sq = 0.f;
    {
        const float4* e4 = (const float4*)efeat;
        const float4* v4 = (const float4*)vfeat;
        #pragma unroll
        for (int i = 0; i < 6; ++i) {
            int q = i * 16 + pp;                // f4 index within 96 (=384 floats)
            float4 r;
            if (q < 32)      r = e4[eg * 32 + q];
            else if (q < 64) r = v4[(size_t)r0 * 32 + (q - 32)];
            else             r = v4[(size_t)c0 * 32 + (q - 64)];
            r.x = bfr(r.x); r.y = bfr(r.y); r.z = bfr(r.z); r.w = bfr(r.w);
            f16x4 h;
            h[0] = (f16_t)r.x; h[1] = (f16_t)r.y; h[2] = (f16_t)r.z; h[3] = (f16_t)r.w;
            *reinterpret_cast<f16x4*>(&X[el * 392 + q * 4]) = h;
            if (q < 32)
                *reinterpret_cast<f16x4*>(&ER[el * 136 + q * 4]) = h;
            s  += r.x + r.y + r.z + r.w;
            sq += r.x*r.x + r.y*r.y + r.z*r.z + r.w*r.w;
        }
        if (pp == 0) {
            cidx[el] = c0;
            unsafeAtomicAdd(&cnts[c0], 1.0f);
        }
    }
    #pragma unroll
    for (int off = 1; off < 16; off <<= 1) {
        s  += __shfl_xor(s, off);
        sq += __shfl_xor(sq, off);
    }
    const float mean = s * (1.f / 384.f);
    const float rstd = 1.f / sqrtf(sq * (1.f / 384.f) - mean * mean + 1e-5f);

    // ---- phase 1: normalize in place (same thread, same addresses -> ordered)
    {
        const float4* g4p = (const float4*)lng;
        const float4* bpp = (const float4*)lnb;
        #pragma unroll
        for (int i = 0; i < 6; ++i) {
            int q = i * 16 + pp;
            f16x4 h = *reinterpret_cast<f16x4*>(&X[el * 392 + q * 4]);
            float4 g = g4p[q]; float4 bb = bpp[q];
            h[0] = (f16_t)(((float)h[0] - mean) * rstd * bfr(g.x) + bfr(bb.x));
            h[1] = (f16_t)(((float)h[1] - mean) * rstd * bfr(g.y) + bfr(bb.y));
            h[2] = (f16_t)(((float)h[2] - mean) * rstd * bfr(g.z) + bfr(bb.z));
            h[3] = (f16_t)(((float)h[3] - mean) * rstd * bfr(g.w) + bfr(bb.w));
            *reinterpret_cast<f16x4*>(&X[el * 392 + q * 4]) = h;
        }
    }
    __syncthreads();

    const int r16 = lane & 15;
    const int g4i = lane >> 4;

    // ---- layer 1: x[64,384] @ ew0 -> h1[64,256]; wave wv covers cols [wv*16,+16)
    {
        f32x4 acc[4] = {};
        const f16_t* bw = pw;                       // ew0 (NT=16)
        #pragma unroll
        for (int ks = 0; ks < 12; ++ks) {
            f16x8 b = *reinterpret_cast<const f16x8*>(
                &bw[((size_t)(ks * 16 + wv) * 64 + lane) * 8]);
            #pragma unroll
            for (int m = 0; m < 4; ++m) {
                f16x8 a = *reinterpret_cast<const f16x8*>(
                    &X[(m * 16 + r16) * 392 + ks * 32 + g4i * 8]);
                acc[m] = MFMA16(a, b, acc[m]);
            }
        }
        __syncthreads();   // all X (stride-392) reads done before overwrite
        int c = wv * 16 + r16;
        float bias = bfr(b0[c]);
        #pragma unroll
        for (int m = 0; m < 4; ++m)
            #pragma unroll
            for (int qi = 0; qi < 4; ++qi) {
                int rr = m * 16 + g4i * 4 + qi;
                X[rr * 264 + c] = (f16_t)fmaxf(acc[m][qi] + bias, 0.f);
            }
    }
    __syncthreads();

    // ---- layer 2: h1 @ ew1 -> h2 (same buffer, stride 264)
    {
        f32x4 acc[4] = {};
        const f16_t* bw = pw + 98304;               // ew1 (NT=16)
        #pragma unroll
        for (int ks = 0; ks < 8; ++ks) {
            f16x8 b = *reinterpret_cast<const f16x8*>(
                &bw[((size_t)(ks * 16 + wv) * 64 + lane) * 8]);
            #pragma unroll
            for (int m = 0; m < 4; ++m) {
                f16x8 a = *reinterpret_cast<const f16x8*>(
                    &X[(m * 16 + r16) * 264 + ks * 32 + g4i * 8]);
                acc[m] = MFMA16(a, b, acc[m]);
            }
        }
        __syncthreads();   // all h1 reads done before overwrite
        int c = wv * 16 + r16;
        float bias = bfr(b1[c]);
        #pragma unroll
        for (int m = 0; m < 4; ++m)
            #pragma unroll
            for (int qi = 0; qi < 4; ++qi) {
                int rr = m * 16 + g4i * 4 + qi;
                X[rr * 264 + c] = (f16_t)fmaxf(acc[m][qi] + bias, 0.f);
            }
    }
    __syncthreads();

    // ---- layer 3 + residual: relu(h2 @ ew2 + b2) + e @ eLin
    // wave (nh = wv&7) covers cols [nh*16,+16); (mh = wv>>3) covers rows [mh*32,+32)
    {
        const int nh = wv & 7;
        const int mh = wv >> 3;
        f32x4 accF[2] = {}, accR[2] = {};
        const f16_t* bw = pw + 163840;              // ew2 (NT=8)
        #pragma unroll
        for (int ks = 0; ks < 8; ++ks) {
            f16x8 b = *reinterpret_cast<const f16x8*>(
                &bw[((size_t)(ks * 8 + nh) * 64 + lane) * 8]);
            #pragma unroll
            for (int m = 0; m < 2; ++m) {
                f16x8 a = *reinterpret_cast<const f16x8*>(
                    &X[(mh * 32 + m * 16 + r16) * 264 + ks * 32 + g4i * 8]);
                accF[m] = MFMA16(a, b, accF[m]);
            }
        }
        const f16_t* bwL = pw + 196608;             // eLin (NT=8)
        #pragma unroll
        for (int ks = 0; ks < 4; ++ks) {
            f16x8 b = *reinterpret_cast<const f16x8*>(
                &bwL[((size_t)(ks * 8 + nh) * 64 + lane) * 8]);
            #pragma unroll
            for (int m = 0; m < 2; ++m) {
                f16x8 a = *reinterpret_cast<const f16x8*>(
                    &ER[(mh * 32 + m * 16 + r16) * 136 + ks * 32 + g4i * 8]);
                accR[m] = MFMA16(a, b, accR[m]);
            }
        }
        int c = nh * 16 + r16;
        float bias = bfr(b2[c]);
        #pragma unroll
        for (int m = 0; m < 2; ++m)
            #pragma unroll
            for (int qi = 0; qi < 4; ++qi) {
                int rr = mh * 32 + m * 16 + g4i * 4 + qi;
                float val = accR[m][qi] + fmaxf(accF[m][qi] + bias, 0.f);
                size_t eg2 = ebase + rr;
                out_e[eg2 * 128 + c] = val;
                unsafeAtomicAdd(&aggr[(size_t)cidx[rr] * 128 + c], val);
            }
    }
}

// ---------------------------------------------------------------------------
// Node kernel: 32 nodes/block, 512 threads (8 waves), ~4 blocks/CU (33 KB LDS).
// node_in = [aggr/clip(cnt) (f32, derived) | bf16(v)]; f16 mids.
// ---------------------------------------------------------------------------
__launch_bounds__(512, 6)
__global__ void node_kernel(
    const float* __restrict__ vfeat, const float* __restrict__ aggr,
    const float* __restrict__ cnts,
    const float* __restrict__ lng, const float* __restrict__ lnb,
    const f16_t* __restrict__ pw,                   // node weight base (nw0)
    const float* __restrict__ b0, const float* __restrict__ b1,
    const float* __restrict__ b2,
    float* __restrict__ out_v, int Nn)
{
    __shared__ f16_t X[32 * 264];
    __shared__ f16_t H1[32 * 264];

    const int t    = threadIdx.x;
    const int lane = t & 63;
    const int wv   = t >> 6;
    const size_t nbase = (size_t)blockIdx.x * 32;

    const int nl = t >> 4;
    const int pp = t & 15;
    const size_t ng = nbase + nl;
    const bool valid = ng < (size_t)Nn;

    float4 d[4];
    float s = 0.f, sq = 0.f;
    {
        float cmax = 1.f;
        if (valid) cmax = fmaxf(cnts[ng], 1.f);
        const float4* a4 = (const float4*)aggr;
        const float4* v4 = (const float4*)vfeat;
        #pragma unroll
        for (int i = 0; i < 4; ++i) {
            int q = i * 16 + pp;                   // f4 index within 64 (=256 floats)
            float4 r = make_float4(0.f, 0.f, 0.f, 0.f);
            if (valid) {
                if (q < 32) {
                    r = a4[ng * 32 + q];
                    r.x = r.x / cmax; r.y = r.y / cmax;
                    r.z = r.z / cmax; r.w = r.w / cmax;   // f32, derived — not rounded
                } else {
                    float4 rv = v4[ng * 32 + (q - 32)];
                    r.x = bfr(rv.x); r.y = bfr(rv.y); r.z = bfr(rv.z); r.w = bfr(rv.w);
                }
            }
            d[i] = r;
            s  += r.x + r.y + r.z + r.w;
            sq += r.x*r.x + r.y*r.y + r.z*r.z + r.w*r.w;
        }
    }
    #pragma unroll
    for (int off = 1; off < 16; off <<= 1) {
        s  += __shfl_xor(s, off);
        sq += __shfl_xor(sq, off);
    }
    const float mean = s * (1.f / 256.f);
    const float rstd = 1.f / sqrtf(sq * (1.f / 256.f) - mean * mean + 1e-5f);
    {
        const float4* g4p = (const float4*)lng;
        const float4* bpp = (const float4*)lnb;
        #pragma unroll
        for (int i = 0; i < 4; ++i) {
            int q = i * 16 + pp;
            float4 g = g4p[q]; float4 bb = bpp[q];
            f16x4 y;
            y[0] = (f16_t)((d[i].x - mean) * rstd * bfr(g.x) + bfr(bb.x));
            y[1] = (f16_t)((d[i].y - mean) * rstd * bfr(g.y) + bfr(bb.y));
            y[2] = (f16_t)((d[i].z - mean) * rstd * bfr(g.z) + bfr(bb.z));
            y[3] = (f16_t)((d[i].w - mean) * rstd * bfr(g.w) + bfr(bb.w));
            *reinterpret_cast<f16x4*>(&X[nl * 264 + q * 4]) = y;
        }
    }
    __syncthreads();

    const int r16 = lane & 15;
    const int g4i = lane >> 4;

    // ---- layer 1: x[32,256] @ nw0 -> h1; wave covers cols [wv*32,+32)
    {
        f32x4 acc[2][2] = {};
        const f16_t* bw = pw;                       // nw0 (NT=16)
        #pragma unroll
        for (int ks = 0; ks < 8; ++ks) {
            f16x8 a0 = *reinterpret_cast<const f16x8*>(&X[r16 * 264 + ks * 32 + g4i * 8]);
            f16x8 a1 = *reinterpret_cast<const f16x8*>(&X[(16 + r16) * 264 + ks * 32 + g4i * 8]);
            #pragma unroll
            for (int n = 0; n < 2; ++n) {
                f16x8 b = *reinterpret_cast<const f16x8*>(
                    &bw[((size_t)(ks * 16 + wv * 2 + n) * 64 + lane) * 8]);
                acc[0][n] = MFMA16(a0, b, acc[0][n]);
                acc[1][n] = MFMA16(a1, b, acc[1][n]);
            }
        }
        #pragma unroll
        for (int n = 0; n < 2; ++n) {
            int c = wv * 32 + n * 16 + r16;
            float bias = bfr(b0[c]);
            #pragma unroll
            for (int m = 0; m < 2; ++m)
                #pragma unroll
                for (int qi = 0; qi < 4; ++qi) {
                    int rr = m * 16 + g4i * 4 + qi;
                    H1[rr * 264 + c] = (f16_t)fmaxf(acc[m][n][qi] + bias, 0.f);
                }
        }
    }
    __syncthreads();

    // ---- layer 2: h1 @ nw1 -> h2 (X region)
    f16_t* h2 = X;
    {
        f32x4 acc[2][2] = {};
        const f16_t* bw = pw + 65536;               // nw1 (NT=16)
        #pragma unroll
        for (int ks = 0; ks < 8; ++ks) {
            f16x8 a0 = *reinterpret_cast<const f16x8*>(&H1[r16 * 264 + ks * 32 + g4i * 8]);
            f16x8 a1 = *reinterpret_cast<const f16x8*>(&H1[(16 + r16) * 264 + ks * 32 + g4i * 8]);
            #pragma unroll
            for (int n = 0; n < 2; ++n) {
                f16x8 b = *reinterpret_cast<const f16x8*>(
                    &bw[((size_t)(ks * 16 + wv * 2 + n) * 64 + lane) * 8]);
                acc[0][n] = MFMA16(a0, b, acc[0][n]);
                acc[1][n] = MFMA16(a1, b, acc[1][n]);
            }
        }
        __syncthreads();
        #pragma unroll
        for (int n = 0; n < 2; ++n) {
            int c = wv * 32 + n * 16 + r16;
            float bias = bfr(b1[c]);
            #pragma unroll
            for (int m = 0; m < 2; ++m)
                #pragma unroll
                for (int qi = 0; qi < 4; ++qi) {
                    int rr = m * 16 + g4i * 4 + qi;
                    h2[rr * 264 + c] = (f16_t)fmaxf(acc[m][n][qi] + bias, 0.f);
                }
        }
    }
    __syncthreads();

    // ---- layer 3 + residual: relu(h2 @ nw2 + b2) + v @ nLin ; cols [wv*16,+16)
    {
        f32x4 accF[2] = {}, accR[2] = {};
        const f16_t* bw = pw + 131072;              // nw2 (NT=8)
        #pragma unroll
        for (int ks = 0; ks < 8; ++ks) {
            f16x8 a0 = *reinterpret_cast<const f16x8*>(&h2[r16 * 264 + ks * 32 + g4i * 8]);
            f16x8 a1 = *reinterpret_cast<const f16x8*>(&h2[(16 + r16) * 264 + ks * 32 + g4i * 8]);
            f16x8 b = *reinterpret_cast<const f16x8*>(
                &bw[((size_t)(ks * 8 + wv) * 64 + lane) * 8]);
            accF[0] = MFMA16(a0, b, accF[0]);
            accF[1] = MFMA16(a1, b, accF[1]);
        }
        const f16_t* bwL = pw + 163840;             // nLin (NT=8)
        #pragma unroll
        for (int ks = 0; ks < 4; ++ks) {
            f16x8 a[2];
            #pragma unroll
            for (int m = 0; m < 2; ++m) {
                size_t rv = nbase + (size_t)(m * 16 + r16);
                if (rv >= (size_t)Nn) rv = (size_t)Nn - 1;   // clamp (rows unused)
                const float* src = &vfeat[rv * 128 + ks * 32 + g4i * 8];
                float4 f0 = *(const float4*)src;
                float4 f1 = *(const float4*)(src + 4);
                f16x8 av;
                av[0] = (f16_t)bfr(f0.x); av[1] = (f16_t)bfr(f0.y);
                av[2] = (f16_t)bfr(f0.z); av[3] = (f16_t)bfr(f0.w);
                av[4] = (f16_t)bfr(f1.x); av[5] = (f16_t)bfr(f1.y);
                av[6] = (f16_t)bfr(f1.z); av[7] = (f16_t)bfr(f1.w);
                a[m] = av;
            }
            f16x8 b = *reinterpret_cast<const f16x8*>(
                &bwL[((size_t)(ks * 8 + wv) * 64 + lane) * 8]);
            accR[0] = MFMA16(a[0], b, accR[0]);
            accR[1] = MFMA16(a[1], b, accR[1]);
        }
        int c = wv * 16 + r16;
        float bias = bfr(b2[c]);
        #pragma unroll
        for (int m = 0; m < 2; ++m)
            #pragma unroll
            for (int qi = 0; qi < 4; ++qi) {
                int rr = m * 16 + g4i * 4 + qi;
                size_t ng2 = nbase + rr;
                if (ng2 < (size_t)Nn) {
                    float val = accR[m][qi] + fmaxf(accF[m][qi] + bias, 0.f);
                    out_v[ng2 * 128 + c] = val;
                }
            }
    }
}

// ---------------------------------------------------------------------------
extern "C" void kernel_launch(void* const* d_in, const int* in_sizes, int n_in,
                              void* d_out, int out_size, void* d_ws, size_t ws_size,
                              hipStream_t stream)
{
    const float* v    = (const float*)d_in[0];
    const float* e    = (const float*)d_in[1];
    const int*   eidx = (const int*)d_in[2];
    const float* elng = (const float*)d_in[3];
    const float* elnb = (const float*)d_in[4];
    const float* ew0  = (const float*)d_in[5];
    const float* eb0  = (const float*)d_in[6];
    const float* ew1  = (const float*)d_in[7];
    const float* eb1  = (const float*)d_in[8];
    const float* ew2  = (const float*)d_in[9];
    const float* eb2  = (const float*)d_in[10];
    const float* eLin = (const float*)d_in[11];
    const float* nlng = (const float*)d_in[12];
    const float* nlnb = (const float*)d_in[13];
    const float* nw0  = (const float*)d_in[14];
    const float* nb0  = (const float*)d_in[15];
    const float* nw1  = (const float*)d_in[16];
    const float* nb1  = (const float*)d_in[17];
    const float* nw2  = (const float*)d_in[18];
    const float* nb2  = (const float*)d_in[19];
    const float* nLin = (const float*)d_in[20];

    const int Nn = in_sizes[0] / 128;
    const int Ee = in_sizes[1] / 128;

    float* out_v = (float*)d_out;
    float* out_e = out_v + (size_t)Nn * 128;

    float* aggr = (float*)d_ws;                       // [Nn][128] f32
    float* cnts = aggr + (size_t)Nn * 128;            // [Nn] f32
    f16_t* packw = (f16_t*)((char*)d_ws + (size_t)Nn * 129 * 4);  // 393216 f16

    hipMemsetAsync(d_ws, 0, (size_t)Nn * 129 * 4, stream);

    pack_weights_kernel<<<192, 256, 0, stream>>>(ew0, ew1, ew2, eLin,
                                                 nw0, nw1, nw2, nLin, packw);

    edge_kernel<<<(Ee + 63) / 64, 1024, 0, stream>>>(v, e, eidx, elng, elnb, packw,
                                                     eb0, eb1, eb2, out_e, aggr, cnts, Ee);

    node_kernel<<<(Nn + 31) / 32, 512, 0, stream>>>(v, aggr, cnts, nlng, nlnb,
                                                    packw + 212992, nb0, nb1, nb2,
                                                    out_v, Nn);
}